// Round 7
// baseline (416.712 us; speedup 1.0000x reference)
//
#include <hip/hip_runtime.h>
#include <math.h>

// TensorTrainGaussian likelihood as a matvec chain:
//   u0 = softmax(wk0_logits); u_{m+1} = R_m(x_n) u_m;  out = log(sum(u_16) + EPS)
//   R_m[i,j] = exp2( (A*x + B)*x + C ),  per-(m,i,j):
// A = -0.5/s^2*log2e, B = mu/s^2*log2e,
// C = (logW - log s - 0.5*log(2pi) - 0.5*mu^2/s^2)*log2e, s = softplus(pre_sigma)
// Params j-quad packed for ds_read_b128; Horner via v_pk_fma_f32.
// exp2 split across pipes: 5/8 pairs via v_exp_f32 (trans pipe), 3/8 via
// packed-FMA polynomial (VALU pipe) -- both pipes run concurrently.

#define TTG_N 32768
#define TTG_M 16
#define TTG_K 64

typedef float f32x2 __attribute__((ext_vector_type(2)));
typedef float f32x4 __attribute__((ext_vector_type(4)));
typedef int   i32x2 __attribute__((ext_vector_type(2)));

static constexpr float kHalfLog2Pi = 0.9189385332046727f;
static constexpr float kEps        = 2.220446049250313e-16f;
static constexpr float kLog2e      = 1.4426950408889634f;

#if defined(__has_builtin)
#if __has_builtin(__builtin_amdgcn_exp2f)
#define TTG_EXP2(x) __builtin_amdgcn_exp2f(x)
#else
#define TTG_EXP2(x) exp2f(x)
#endif
#else
#define TTG_EXP2(x) exp2f(x)
#endif

// d = a*b + c, all genuine 64-bit pairs -> zero operand shuffling
#define PKFMA(d, a, b, c) \
  asm("v_pk_fma_f32 %0, %1, %2, %3" : "=v"(d) : "v"(a), "v"(b), "v"(c))

// Packed exp2 on the full-rate VALU pipe: magic-number range reduction,
// deg-5 Horner (5 pk_fma), scale via integer exponent construction.
// Clamp at -126 keeps the bit-trick scale out of subnormal/sign wrap.
static __device__ __forceinline__ f32x2 ttg_exp2p(f32x2 t) {
  f32x2 tc, k, n, f, p;
  tc[0] = fmaxf(t[0], -126.0f);
  tc[1] = fmaxf(t[1], -126.0f);
  k[0] = tc[0] + 12582912.0f;  // 1.5*2^23; RNE -> integer in mantissa
  k[1] = tc[1] + 12582912.0f;
  n[0] = k[0] - 12582912.0f;
  n[1] = k[1] - 12582912.0f;
  f[0] = tc[0] - n[0];         // f in [-0.5, 0.5]
  f[1] = tc[1] - n[1];
  const f32x2 c5  = {1.3333558146e-3f, 1.3333558146e-3f};
  const f32x2 c4  = {9.6181291076e-3f, 9.6181291076e-3f};
  const f32x2 c3  = {5.5504108665e-2f, 5.5504108665e-2f};
  const f32x2 c2  = {2.4022650696e-1f, 2.4022650696e-1f};
  const f32x2 c1  = {6.9314718056e-1f, 6.9314718056e-1f};
  const f32x2 one = {1.0f, 1.0f};
  PKFMA(p, c5, f, c4);
  PKFMA(p, p, f, c3);
  PKFMA(p, p, f, c2);
  PKFMA(p, p, f, c1);
  PKFMA(p, p, f, one);
  i32x2 kb;
  __builtin_memcpy(&kb, &k, 8);
  kb = (kb << 23) + 0x3f800000;  // 2^n bits (n from k's mantissa low bits)
  f32x2 s;
  __builtin_memcpy(&s, &kb, 8);
  return p * s;
}

// ---------------- prep: wk0 = softmax(wk0_logits) ----------------
__global__ void ttg_prep_wk0(const float* __restrict__ logits,
                             float* __restrict__ wk0) {
  int i = threadIdx.x;  // 64 threads = 1 wave
  float l = logits[i];
  float mx = l;
  for (int d = 1; d < 64; d <<= 1) mx = fmaxf(mx, __shfl_xor(mx, d));
  float e = expf(l - mx);
  float s = e;
  for (int d = 1; d < 64; d <<= 1) s += __shfl_xor(s, d);
  wk0[i] = e / s;
}

// ---------------- prep: Horner coefficients, j-quad packed ----------------
// One wave per (m, j); lane = i. log_softmax over i (axis=1 of (M,K,K)).
// Per m (12288 floats): A4 [j/4][i][4] @0, B4 @4096, C4 @8192.
__global__ void ttg_prep_params(const float* __restrict__ W,
                                const float* __restrict__ mu,
                                const float* __restrict__ ps,
                                float* __restrict__ P) {
  int b = blockIdx.x;
  int m = b >> 6;
  int j = b & 63;
  int i = threadIdx.x;
  int idx = (m * TTG_K + i) * TTG_K + j;  // [m][i][j]

  float w = W[idx];
  float mx = w;
  for (int d = 1; d < 64; d <<= 1) mx = fmaxf(mx, __shfl_xor(mx, d));
  float e = expf(w - mx);
  float s = e;
  for (int d = 1; d < 64; d <<= 1) s += __shfl_xor(s, d);
  float lw = w - mx - logf(s);  // log_softmax over i

  float mv  = mu[idx];
  float sig = log1pf(expf(ps[idx]));  // jax.nn.softplus
  float inv2 = 1.0f / (sig * sig);
  float A = -0.5f * inv2 * kLog2e;
  float B = mv * inv2 * kLog2e;
  float C = (lw - logf(sig) - kHalfLog2Pi - 0.5f * mv * mv * inv2) * kLog2e;

  float* base = P + (size_t)m * 12288;
  int pi = ((j >> 2) * TTG_K + i) * 4 + (j & 3);
  base[pi]        = A;
  base[4096 + pi] = B;
  base[8192 + pi] = C;
}

// ---------------- main chain kernel ----------------
// 1024 threads (16 waves), 64 samples/block; wave w owns samples w*4..w*4+3.
// lane = i. 68 KB LDS -> 2 blocks/CU. Params staged per step in a SHORT
// epilogue (no cross-loop prefetch regs; R4 spill lesson). j4 loop fully
// unrolled: every ds_read address is base + imm offset.
__global__ __launch_bounds__(1024, 4) void ttg_main(
    const float* __restrict__ X, const float* __restrict__ P,
    const float* __restrict__ wk0, float* __restrict__ out) {
  __shared__ __align__(16) float prA[TTG_K * TTG_K];  // 16 KB [j/4][i][4]
  __shared__ __align__(16) float prB[TTG_K * TTG_K];  // 16 KB
  __shared__ __align__(16) float prC[TTG_K * TTG_K];  // 16 KB
  __shared__ __align__(16) float ub[64 * TTG_K];      // 16 KB [sample][j]
  __shared__ __align__(16) float xbT[TTG_M * 64];     //  4 KB [m][sample]

  const int tid  = threadIdx.x;
  const int lane = tid & 63;
  const int wv   = __builtin_amdgcn_readfirstlane(tid >> 6);  // 0..15
  const int blk  = blockIdx.x;

  // stage X transposed: xbT[m][s] = X[blk*64+s][m]
  if (tid < 256) {
    float4 v = ((const float4*)X)[blk * 256 + tid];
    int s = tid >> 2, f0 = (tid & 3) * 4;
    xbT[(f0 + 0) * 64 + s] = v.x;
    xbT[(f0 + 1) * 64 + s] = v.y;
    xbT[(f0 + 2) * 64 + s] = v.z;
    xbT[(f0 + 3) * 64 + s] = v.w;
  }
  // u0[s][j] = wk0[j]
#pragma unroll
  for (int r = 0; r < 4; ++r) {
    int idx = tid + r * 1024;
    ub[idx] = wk0[idx & 63];
  }
  // stage m=0 params (3072 float4 / 1024 threads)
  {
    const float4* src = (const float4*)P;
    ((float4*)prA)[tid] = src[tid];
    ((float4*)prB)[tid] = src[1024 + tid];
    ((float4*)prC)[tid] = src[2048 + tid];
  }
  __syncthreads();

  f32x2 aL0, aH0, aL1, aH1, aL2, aH2, aL3, aH3;
  for (int m = 0; m < TTG_M; ++m) {
    // wave-uniform x splat pairs for this wave's 4 samples (loop-invariant)
    const float* xr = xbT + m * 64 + wv * 4;
    const f32x2 xs0 = {xr[0], xr[0]};
    const f32x2 xs1 = {xr[1], xr[1]};
    const f32x2 xs2 = {xr[2], xr[2]};
    const f32x2 xs3 = {xr[3], xr[3]};

    aL0 = aH0 = aL1 = aH1 = aL2 = aH2 = aL3 = aH3 = (f32x2){0.f, 0.f};
    const f32x4* pA = ((const f32x4*)prA) + lane;
    const f32x4* pB = ((const f32x4*)prB) + lane;
    const f32x4* pC = ((const f32x4*)prC) + lane;
    const f32x4* pU = (const f32x4*)(ub + wv * 4 * TTG_K);  // 4 rows x 16 quads

// PHI=1: hi-pair exp2 via packed polynomial (VALU); else v_exp_f32 (trans).
#define TTG_S(S, XS, ACCL, ACCH, PHI)                                         \
    {                                                                         \
      const f32x4 u4 = pU[(S) * 16 + j4];  /* b128 broadcast */               \
      f32x2 h0, h1, tlo, thi;                                                 \
      PKFMA(h0, alo, XS, blo);                                                \
      PKFMA(tlo, h0, XS, clo);                                                \
      PKFMA(h1, ahi, XS, bhi);                                                \
      PKFMA(thi, h1, XS, chi);                                                \
      ACCL[0] = fmaf(TTG_EXP2(tlo[0]), u4.x, ACCL[0]);                        \
      ACCL[1] = fmaf(TTG_EXP2(tlo[1]), u4.y, ACCL[1]);                        \
      if (PHI) {                                                              \
        f32x2 e2 = ttg_exp2p(thi);                                            \
        const f32x2 uh = {u4.z, u4.w};                                        \
        PKFMA(ACCH, e2, uh, ACCH);                                            \
      } else {                                                                \
        ACCH[0] = fmaf(TTG_EXP2(thi[0]), u4.z, ACCH[0]);                      \
        ACCH[1] = fmaf(TTG_EXP2(thi[1]), u4.w, ACCH[1]);                      \
      }                                                                       \
    }

#pragma unroll
    for (int j4 = 0; j4 < 16; ++j4) {
      const f32x4 a4 = pA[j4 * 64];  // ds_read_b128, imm offset
      const f32x4 b4 = pB[j4 * 64];
      const f32x4 c4 = pC[j4 * 64];
      const f32x2 alo = __builtin_shufflevector(a4, a4, 0, 1);
      const f32x2 ahi = __builtin_shufflevector(a4, a4, 2, 3);
      const f32x2 blo = __builtin_shufflevector(b4, b4, 0, 1);
      const f32x2 bhi = __builtin_shufflevector(b4, b4, 2, 3);
      const f32x2 clo = __builtin_shufflevector(c4, c4, 0, 1);
      const f32x2 chi = __builtin_shufflevector(c4, c4, 2, 3);
      TTG_S(0, xs0, aL0, aH0, 0)
      TTG_S(1, xs1, aL1, aH1, 1)
      TTG_S(2, xs2, aL2, aH2, 1)
      TTG_S(3, xs3, aL3, aH3, 1)
    }
#undef TTG_S

    if (m < TTG_M - 1) {
      __syncthreads();  // all waves done reading ub/params
      // u_{m+1}[s][i]: lane i writes its entry for the wave's 4 samples
      float* ud = ub + wv * 4 * TTG_K + lane;
      ud[0 * TTG_K] = aL0[0] + aL0[1] + aH0[0] + aH0[1];
      ud[1 * TTG_K] = aL1[0] + aL1[1] + aH1[0] + aH1[1];
      ud[2 * TTG_K] = aL2[0] + aL2[1] + aH2[0] + aH2[1];
      ud[3 * TTG_K] = aL3[0] + aL3[1] + aH3[0] + aH3[1];
      // stage next step's params: SHORT live range (load -> store)
      const float4* src = (const float4*)(P + (size_t)(m + 1) * 12288);
      float4 pf0 = src[tid];
      float4 pf1 = src[tid + 1024];
      float4 pf2 = src[tid + 2048];
      ((float4*)prA)[tid] = pf0;
      ((float4*)prB)[tid] = pf1;
      ((float4*)prC)[tid] = pf2;
      __syncthreads();
    }
  }

  // likelihood_s = sum_i -> wave shuffle reduce, then log
  float r[4] = {aL0[0] + aL0[1] + aH0[0] + aH0[1],
                aL1[0] + aL1[1] + aH1[0] + aH1[1],
                aL2[0] + aL2[1] + aH2[0] + aH2[1],
                aL3[0] + aL3[1] + aH3[0] + aH3[1]};
#pragma unroll
  for (int c = 0; c < 4; ++c) {
#pragma unroll
    for (int d = 1; d < 64; d <<= 1) r[c] += __shfl_xor(r[c], d);
  }
  if (lane == 0) {
    const int s0 = blk * 64 + wv * 4;
#pragma unroll
    for (int c = 0; c < 4; ++c) out[s0 + c] = logf(r[c] + kEps);
  }
}

extern "C" void kernel_launch(void* const* d_in, const int* in_sizes, int n_in,
                              void* d_out, int out_size, void* d_ws, size_t ws_size,
                              hipStream_t stream) {
  const float* X   = (const float*)d_in[0];  // (N, M)
  const float* wl  = (const float*)d_in[1];  // (1, K)
  const float* W   = (const float*)d_in[2];  // (M, K, K)
  const float* mu  = (const float*)d_in[3];  // (M, K, K)
  const float* ps  = (const float*)d_in[4];  // (M, K, K)
  float* out = (float*)d_out;

  float* wk0 = (float*)d_ws;
  float* P   = wk0 + 256;

  ttg_prep_wk0<<<1, 64, 0, stream>>>(wl, wk0);
  ttg_prep_params<<<TTG_M * TTG_K, 64, 0, stream>>>(W, mu, ps, P);
  ttg_main<<<TTG_N / 64, 1024, 0, stream>>>(X, P, wk0, out);
}

// Round 8
// 306.388 us; speedup vs baseline: 1.3601x; 1.3601x over previous
//
#include <hip/hip_runtime.h>
#include <math.h>

// TensorTrainGaussian likelihood as a matvec chain:
//   u0 = softmax(wk0_logits); u_{m+1} = R_m(x_n) u_m;  out = log(sum(u_16) + EPS)
//   R_m[i,j] = exp2( A*x^2 + B*x + C ),  per-(m,i,j):
// A = -0.5/s^2*log2e, B = mu/s^2*log2e,
// C = (logW - log s - 0.5*log(2pi) - 0.5*mu^2/s^2)*log2e, s = softplus(pre_sigma)
// R8: pure scalar inner loop (no inline asm, no packed math -- shared issue
// port makes pk/poly useless); t = fmaf(a,y,fmaf(b,x,c)) with y=x^2 hoisted.

#define TTG_N 32768
#define TTG_M 16
#define TTG_K 64

typedef float f32x4 __attribute__((ext_vector_type(4)));

static constexpr float kHalfLog2Pi = 0.9189385332046727f;
static constexpr float kEps        = 2.220446049250313e-16f;
static constexpr float kLog2e      = 1.4426950408889634f;

#if defined(__has_builtin)
#if __has_builtin(__builtin_amdgcn_exp2f)
#define TTG_EXP2(x) __builtin_amdgcn_exp2f(x)
#else
#define TTG_EXP2(x) exp2f(x)
#endif
#else
#define TTG_EXP2(x) exp2f(x)
#endif

// ---------------- prep: wk0 = softmax(wk0_logits) ----------------
__global__ void ttg_prep_wk0(const float* __restrict__ logits,
                             float* __restrict__ wk0) {
  int i = threadIdx.x;  // 64 threads = 1 wave
  float l = logits[i];
  float mx = l;
  for (int d = 1; d < 64; d <<= 1) mx = fmaxf(mx, __shfl_xor(mx, d));
  float e = expf(l - mx);
  float s = e;
  for (int d = 1; d < 64; d <<= 1) s += __shfl_xor(s, d);
  wk0[i] = e / s;
}

// ---------------- prep: Horner coefficients, j-quad packed ----------------
// One wave per (m, j); lane = i. log_softmax over i (axis=1 of (M,K,K)).
// Per m (12288 floats): A4 [j/4][i][4] @0, B4 @4096, C4 @8192.
__global__ void ttg_prep_params(const float* __restrict__ W,
                                const float* __restrict__ mu,
                                const float* __restrict__ ps,
                                float* __restrict__ P) {
  int b = blockIdx.x;
  int m = b >> 6;
  int j = b & 63;
  int i = threadIdx.x;
  int idx = (m * TTG_K + i) * TTG_K + j;  // [m][i][j]

  float w = W[idx];
  float mx = w;
  for (int d = 1; d < 64; d <<= 1) mx = fmaxf(mx, __shfl_xor(mx, d));
  float e = expf(w - mx);
  float s = e;
  for (int d = 1; d < 64; d <<= 1) s += __shfl_xor(s, d);
  float lw = w - mx - logf(s);  // log_softmax over i

  float mv  = mu[idx];
  float sig = log1pf(expf(ps[idx]));  // jax.nn.softplus
  float inv2 = 1.0f / (sig * sig);
  float A = -0.5f * inv2 * kLog2e;
  float B = mv * inv2 * kLog2e;
  float C = (lw - logf(sig) - kHalfLog2Pi - 0.5f * mv * mv * inv2) * kLog2e;

  float* base = P + (size_t)m * 12288;
  int pi = ((j >> 2) * TTG_K + i) * 4 + (j & 3);
  base[pi]        = A;
  base[4096 + pi] = B;
  base[8192 + pi] = C;
}

// ---------------- main chain kernel ----------------
// 1024 threads (16 waves), 64 samples/block; wave w owns samples w*4..w*4+3.
// lane = i. 68 KB LDS -> 2 blocks/CU (8 waves/SIMD). Next-step params
// register-prefetched across the j4 loop (12 VGPRs; cap 64 so no spill --
// R4's spill came from the 32-reg corset, not the prefetch). j4 loop fully
// unrolled: every ds_read address is base + imm offset.
__global__ __launch_bounds__(1024, 4) void ttg_main(
    const float* __restrict__ X, const float* __restrict__ P,
    const float* __restrict__ wk0, float* __restrict__ out) {
  __shared__ __align__(16) float prA[TTG_K * TTG_K];  // 16 KB [j/4][i][4]
  __shared__ __align__(16) float prB[TTG_K * TTG_K];  // 16 KB
  __shared__ __align__(16) float prC[TTG_K * TTG_K];  // 16 KB
  __shared__ __align__(16) float ub[64 * TTG_K];      // 16 KB [sample][j]
  __shared__ __align__(16) float xbT[TTG_M * 64];     //  4 KB [m][sample]

  const int tid  = threadIdx.x;
  const int lane = tid & 63;
  const int wv   = __builtin_amdgcn_readfirstlane(tid >> 6);  // 0..15
  const int blk  = blockIdx.x;

  // stage X transposed: xbT[m][s] = X[blk*64+s][m]
  if (tid < 256) {
    float4 v = ((const float4*)X)[blk * 256 + tid];
    int s = tid >> 2, f0 = (tid & 3) * 4;
    xbT[(f0 + 0) * 64 + s] = v.x;
    xbT[(f0 + 1) * 64 + s] = v.y;
    xbT[(f0 + 2) * 64 + s] = v.z;
    xbT[(f0 + 3) * 64 + s] = v.w;
  }
  // u0[s][j] = wk0[j]
#pragma unroll
  for (int r = 0; r < 4; ++r) {
    int idx = tid + r * 1024;
    ub[idx] = wk0[idx & 63];
  }
  // stage m=0 params (3072 float4 / 1024 threads)
  {
    const float4* src = (const float4*)P;
    ((float4*)prA)[tid] = src[tid];
    ((float4*)prB)[tid] = src[1024 + tid];
    ((float4*)prC)[tid] = src[2048 + tid];
  }
  __syncthreads();

  float acc0, acc1, acc2, acc3;
  for (int m = 0; m < TTG_M; ++m) {
    // prefetch next step's params NOW; commit after the end-of-step barrier.
    // Live range spans the loop but is only 12 VGPRs.
    float4 pf0, pf1, pf2;
    if (m < TTG_M - 1) {
      const float4* src = (const float4*)(P + (size_t)(m + 1) * 12288);
      pf0 = src[tid];
      pf1 = src[tid + 1024];
      pf2 = src[tid + 2048];
    }
    // wave-uniform x and x^2 for this wave's 4 samples (loop-invariant)
    const float* xr = xbT + m * 64 + wv * 4;
    const float x0 = xr[0], x1 = xr[1], x2 = xr[2], x3 = xr[3];
    const float y0 = x0 * x0, y1 = x1 * x1, y2 = x2 * x2, y3 = x3 * x3;

    acc0 = acc1 = acc2 = acc3 = 0.f;
    const f32x4* pA = ((const f32x4*)prA) + lane;
    const f32x4* pB = ((const f32x4*)prB) + lane;
    const f32x4* pC = ((const f32x4*)prC) + lane;
    const f32x4* pU = (const f32x4*)(ub + wv * 4 * TTG_K);  // 4 rows x 16 quads

#pragma unroll
    for (int j4 = 0; j4 < 16; ++j4) {
      const f32x4 a4 = pA[j4 * 64];  // ds_read_b128, imm offset
      const f32x4 b4 = pB[j4 * 64];
      const f32x4 c4 = pC[j4 * 64];
      const f32x4 u0q = pU[j4];       // b128 broadcast, sample 0
      const f32x4 u1q = pU[16 + j4];  // sample 1
      const f32x4 u2q = pU[32 + j4];  // sample 2
      const f32x4 u3q = pU[48 + j4];  // sample 3
#pragma unroll
      for (int q = 0; q < 4; ++q) {
        const float a = a4[q], b = b4[q], c = c4[q];
        float t0 = fmaf(a, y0, fmaf(b, x0, c));
        float t1 = fmaf(a, y1, fmaf(b, x1, c));
        float t2 = fmaf(a, y2, fmaf(b, x2, c));
        float t3 = fmaf(a, y3, fmaf(b, x3, c));
        acc0 = fmaf(TTG_EXP2(t0), u0q[q], acc0);
        acc1 = fmaf(TTG_EXP2(t1), u1q[q], acc1);
        acc2 = fmaf(TTG_EXP2(t2), u2q[q], acc2);
        acc3 = fmaf(TTG_EXP2(t3), u3q[q], acc3);
      }
    }

    if (m < TTG_M - 1) {
      __syncthreads();  // all waves done reading ub/params
      // u_{m+1}[s][i]: lane i writes its entry for the wave's 4 samples
      float* ud = ub + wv * 4 * TTG_K + lane;
      ud[0 * TTG_K] = acc0;
      ud[1 * TTG_K] = acc1;
      ud[2 * TTG_K] = acc2;
      ud[3 * TTG_K] = acc3;
      // commit prefetched params
      ((float4*)prA)[tid] = pf0;
      ((float4*)prB)[tid] = pf1;
      ((float4*)prC)[tid] = pf2;
      __syncthreads();
    }
  }

  // likelihood_s = sum_i -> wave shuffle reduce, then log
  float r[4] = {acc0, acc1, acc2, acc3};
#pragma unroll
  for (int c = 0; c < 4; ++c) {
#pragma unroll
    for (int d = 1; d < 64; d <<= 1) r[c] += __shfl_xor(r[c], d);
  }
  if (lane == 0) {
    const int s0 = blk * 64 + wv * 4;
#pragma unroll
    for (int c = 0; c < 4; ++c) out[s0 + c] = logf(r[c] + kEps);
  }
}

extern "C" void kernel_launch(void* const* d_in, const int* in_sizes, int n_in,
                              void* d_out, int out_size, void* d_ws, size_t ws_size,
                              hipStream_t stream) {
  const float* X   = (const float*)d_in[0];  // (N, M)
  const float* wl  = (const float*)d_in[1];  // (1, K)
  const float* W   = (const float*)d_in[2];  // (M, K, K)
  const float* mu  = (const float*)d_in[3];  // (M, K, K)
  const float* ps  = (const float*)d_in[4];  // (M, K, K)
  float* out = (float*)d_out;

  float* wk0 = (float*)d_ws;
  float* P   = wk0 + 256;

  ttg_prep_wk0<<<1, 64, 0, stream>>>(wl, wk0);
  ttg_prep_params<<<TTG_M * TTG_K, 64, 0, stream>>>(W, mu, ps, P);
  ttg_main<<<TTG_N / 64, 1024, 0, stream>>>(X, P, wk0, out);
}

// Round 9
// 302.509 us; speedup vs baseline: 1.3775x; 1.0128x over previous
//
#include <hip/hip_runtime.h>
#include <math.h>

// TensorTrainGaussian likelihood as a matvec chain:
//   u0 = softmax(wk0_logits); u_{m+1} = R_m(x_n) u_m;  out = log(sum(u_16) + EPS)
//   R_m[i,j] = exp2( A*x^2 + B*x + C ),  per-(m,i,j):
// A = -0.5/s^2*log2e, B = mu/s^2*log2e,
// C = (logW - log s - 0.5*log(2pi) - 0.5*mu^2/s^2)*log2e, s = softplus(pre_sigma)
// R9: issue-port-minimal scalar inner loop; 8 samples/wave to amortize
// param ds_reads + x setup; 512-thread blocks (2 staggering blocks/CU).

#define TTG_N 32768
#define TTG_M 16
#define TTG_K 64

typedef float f32x4 __attribute__((ext_vector_type(4)));

static constexpr float kHalfLog2Pi = 0.9189385332046727f;
static constexpr float kEps        = 2.220446049250313e-16f;
static constexpr float kLog2e      = 1.4426950408889634f;

#if defined(__has_builtin)
#if __has_builtin(__builtin_amdgcn_exp2f)
#define TTG_EXP2(x) __builtin_amdgcn_exp2f(x)
#else
#define TTG_EXP2(x) exp2f(x)
#endif
#else
#define TTG_EXP2(x) exp2f(x)
#endif

// ---------------- prep: wk0 = softmax(wk0_logits) ----------------
__global__ void ttg_prep_wk0(const float* __restrict__ logits,
                             float* __restrict__ wk0) {
  int i = threadIdx.x;  // 64 threads = 1 wave
  float l = logits[i];
  float mx = l;
  for (int d = 1; d < 64; d <<= 1) mx = fmaxf(mx, __shfl_xor(mx, d));
  float e = expf(l - mx);
  float s = e;
  for (int d = 1; d < 64; d <<= 1) s += __shfl_xor(s, d);
  wk0[i] = e / s;
}

// ---------------- prep: Horner coefficients, j-quad packed ----------------
// One wave per (m, j); lane = i. log_softmax over i (axis=1 of (M,K,K)).
// Per m (12288 floats): A4 [j/4][i][4] @0, B4 @4096, C4 @8192.
__global__ void ttg_prep_params(const float* __restrict__ W,
                                const float* __restrict__ mu,
                                const float* __restrict__ ps,
                                float* __restrict__ P) {
  int b = blockIdx.x;
  int m = b >> 6;
  int j = b & 63;
  int i = threadIdx.x;
  int idx = (m * TTG_K + i) * TTG_K + j;  // [m][i][j]

  float w = W[idx];
  float mx = w;
  for (int d = 1; d < 64; d <<= 1) mx = fmaxf(mx, __shfl_xor(mx, d));
  float e = expf(w - mx);
  float s = e;
  for (int d = 1; d < 64; d <<= 1) s += __shfl_xor(s, d);
  float lw = w - mx - logf(s);  // log_softmax over i

  float mv  = mu[idx];
  float sig = log1pf(expf(ps[idx]));  // jax.nn.softplus
  float inv2 = 1.0f / (sig * sig);
  float A = -0.5f * inv2 * kLog2e;
  float B = mv * inv2 * kLog2e;
  float C = (lw - logf(sig) - kHalfLog2Pi - 0.5f * mv * mv * inv2) * kLog2e;

  float* base = P + (size_t)m * 12288;
  int pi = ((j >> 2) * TTG_K + i) * 4 + (j & 3);
  base[pi]        = A;
  base[4096 + pi] = B;
  base[8192 + pi] = C;
}

// ---------------- main chain kernel ----------------
// 512 threads (8 waves), 64 samples/block; wave w owns samples w*8..w*8+7.
// lane = i. 68 KB LDS -> 2 blocks/CU (4 waves/SIMD), staggered barriers.
// Short-epilogue param staging (VGPR <= 64; R4 spill lesson). j4 loop fully
// unrolled: every ds_read address is base + imm offset.
__global__ __launch_bounds__(512, 4) void ttg_main(
    const float* __restrict__ X, const float* __restrict__ P,
    const float* __restrict__ wk0, float* __restrict__ out) {
  __shared__ __align__(16) float prA[TTG_K * TTG_K];  // 16 KB [j/4][i][4]
  __shared__ __align__(16) float prB[TTG_K * TTG_K];  // 16 KB
  __shared__ __align__(16) float prC[TTG_K * TTG_K];  // 16 KB
  __shared__ __align__(16) float ub[64 * TTG_K];      // 16 KB [sample][j]
  __shared__ __align__(16) float xbT[TTG_M * 64];     //  4 KB [m][sample]

  const int tid  = threadIdx.x;
  const int lane = tid & 63;
  const int wv   = __builtin_amdgcn_readfirstlane(tid >> 6);  // 0..7
  const int blk  = blockIdx.x;

  // stage X transposed: xbT[m][s] = X[blk*64+s][m]
  if (tid < 256) {
    float4 v = ((const float4*)X)[blk * 256 + tid];
    int s = tid >> 2, f0 = (tid & 3) * 4;
    xbT[(f0 + 0) * 64 + s] = v.x;
    xbT[(f0 + 1) * 64 + s] = v.y;
    xbT[(f0 + 2) * 64 + s] = v.z;
    xbT[(f0 + 3) * 64 + s] = v.w;
  }
  // u0[s][j] = wk0[j]
#pragma unroll
  for (int r = 0; r < 8; ++r) {
    int idx = tid + r * 512;
    ub[idx] = wk0[idx & 63];
  }
  // stage m=0 params (3072 float4 / 512 threads)
  {
    const float4* src = (const float4*)P;
#pragma unroll
    for (int r = 0; r < 2; ++r) {
      ((float4*)prA)[tid + r * 512] = src[tid + r * 512];
      ((float4*)prB)[tid + r * 512] = src[1024 + tid + r * 512];
      ((float4*)prC)[tid + r * 512] = src[2048 + tid + r * 512];
    }
  }
  __syncthreads();

  float acc0, acc1, acc2, acc3, acc4, acc5, acc6, acc7;
  for (int m = 0; m < TTG_M; ++m) {
    // wave-uniform x and x^2 for this wave's 8 samples (loop-invariant)
    const float* xr = xbT + m * 64 + wv * 8;
    const float x0 = xr[0], x1 = xr[1], x2 = xr[2], x3 = xr[3];
    const float x4 = xr[4], x5 = xr[5], x6 = xr[6], x7 = xr[7];
    const float y0 = x0 * x0, y1 = x1 * x1, y2 = x2 * x2, y3 = x3 * x3;
    const float y4 = x4 * x4, y5 = x5 * x5, y6 = x6 * x6, y7 = x7 * x7;

    acc0 = acc1 = acc2 = acc3 = acc4 = acc5 = acc6 = acc7 = 0.f;
    const f32x4* pA = ((const f32x4*)prA) + lane;
    const f32x4* pB = ((const f32x4*)prB) + lane;
    const f32x4* pC = ((const f32x4*)prC) + lane;
    const f32x4* pU = (const f32x4*)(ub + wv * 8 * TTG_K);  // 8 rows x 16 quads

// One sample: u-quad broadcast read + 4x (2 FMA + exp + fmac).
#define TTG_S(S, XS, YS, ACC)                                                 \
    {                                                                         \
      const f32x4 u4 = pU[(S) * 16 + j4];                                     \
      float t0 = fmaf(a4[0], YS, fmaf(b4[0], XS, c4[0]));                     \
      float t1 = fmaf(a4[1], YS, fmaf(b4[1], XS, c4[1]));                     \
      float t2 = fmaf(a4[2], YS, fmaf(b4[2], XS, c4[2]));                     \
      float t3 = fmaf(a4[3], YS, fmaf(b4[3], XS, c4[3]));                     \
      ACC = fmaf(TTG_EXP2(t0), u4[0], ACC);                                   \
      ACC = fmaf(TTG_EXP2(t1), u4[1], ACC);                                   \
      ACC = fmaf(TTG_EXP2(t2), u4[2], ACC);                                   \
      ACC = fmaf(TTG_EXP2(t3), u4[3], ACC);                                   \
    }

#pragma unroll
    for (int j4 = 0; j4 < 16; ++j4) {
      const f32x4 a4 = pA[j4 * 64];  // ds_read_b128, imm offset
      const f32x4 b4 = pB[j4 * 64];
      const f32x4 c4 = pC[j4 * 64];
      TTG_S(0, x0, y0, acc0)
      TTG_S(1, x1, y1, acc1)
      TTG_S(2, x2, y2, acc2)
      TTG_S(3, x3, y3, acc3)
      TTG_S(4, x4, y4, acc4)
      TTG_S(5, x5, y5, acc5)
      TTG_S(6, x6, y6, acc6)
      TTG_S(7, x7, y7, acc7)
    }
#undef TTG_S

    if (m < TTG_M - 1) {
      __syncthreads();  // all waves done reading ub/params
      // u_{m+1}[s][i]: lane i writes its entry for the wave's 8 samples
      float* ud = ub + wv * 8 * TTG_K + lane;
      ud[0 * TTG_K] = acc0;
      ud[1 * TTG_K] = acc1;
      ud[2 * TTG_K] = acc2;
      ud[3 * TTG_K] = acc3;
      ud[4 * TTG_K] = acc4;
      ud[5 * TTG_K] = acc5;
      ud[6 * TTG_K] = acc6;
      ud[7 * TTG_K] = acc7;
      // stage next step's params: SHORT live range (load -> store)
      const float4* src = (const float4*)(P + (size_t)(m + 1) * 12288);
#pragma unroll
      for (int r = 0; r < 2; ++r) {
        float4 va = src[tid + r * 512];
        float4 vb = src[1024 + tid + r * 512];
        float4 vc = src[2048 + tid + r * 512];
        ((float4*)prA)[tid + r * 512] = va;
        ((float4*)prB)[tid + r * 512] = vb;
        ((float4*)prC)[tid + r * 512] = vc;
      }
      __syncthreads();
    }
  }

  // likelihood_s = sum_i -> wave shuffle reduce, then log
  float r[8] = {acc0, acc1, acc2, acc3, acc4, acc5, acc6, acc7};
#pragma unroll
  for (int c = 0; c < 8; ++c) {
#pragma unroll
    for (int d = 1; d < 64; d <<= 1) r[c] += __shfl_xor(r[c], d);
  }
  if (lane == 0) {
    const int s0 = blk * 64 + wv * 8;
#pragma unroll
    for (int c = 0; c < 8; ++c) out[s0 + c] = logf(r[c] + kEps);
  }
}

extern "C" void kernel_launch(void* const* d_in, const int* in_sizes, int n_in,
                              void* d_out, int out_size, void* d_ws, size_t ws_size,
                              hipStream_t stream) {
  const float* X   = (const float*)d_in[0];  // (N, M)
  const float* wl  = (const float*)d_in[1];  // (1, K)
  const float* W   = (const float*)d_in[2];  // (M, K, K)
  const float* mu  = (const float*)d_in[3];  // (M, K, K)
  const float* ps  = (const float*)d_in[4];  // (M, K, K)
  float* out = (float*)d_out;

  float* wk0 = (float*)d_ws;
  float* P   = wk0 + 256;

  ttg_prep_wk0<<<1, 64, 0, stream>>>(wl, wk0);
  ttg_prep_params<<<TTG_M * TTG_K, 64, 0, stream>>>(W, mu, ps, P);
  ttg_main<<<TTG_N / 64, 512, 0, stream>>>(X, P, wk0, out);
}